// Round 6
// baseline (259.699 us; speedup 1.0000x reference)
//
#include <hip/hip_runtime.h>
#include <math.h>

#define Bb 8
#define Tt 256
#define MEL 128
#define Dd 192
#define NCc 20
#define ND 4                  // delta ranks (updates at t%64==0)
#define NT 32                 // theta ranks (updates at t%8==0)
#define ETAc 0.9f
#define LRc 0.1f
#define MDEC 0.99f            // 1 - ALPHA
#define EPSc 1e-5f
#define PT 2                  // pipeline rows per block
#define RTT 8                 // retrieve rows per block
#define PADD 196              // padded LDS row

__device__ __forceinline__ float sigmoidf_(float x) {
    return 1.0f / (1.0f + __expf(-x));
}

// coefficient of (k_i err_i^T) in M_n, valid for i<=n
__device__ __forceinline__ float memcoef(int n, int i) {
    float m = LRc, pw = LRc;
    for (int nn = i + 1; nn <= n; nn++) { pw *= ETAc; m = MDEC * m + pw; }
    return m;
}

__device__ __forceinline__ float dot4(float4 a, float4 b) {
    return a.x * b.x + a.y * b.y + a.z * b.z + a.w * b.w;
}

// ---------------------------------------------------------------------------
// setup: grid 250 x 192.
//  [0,192)   Wavo row m = Wv_a[m,:] @ Wo_a (k-outer coalesced)
//  [192]     b_avo
//  [193,241) WqtT transpose (4 rows each)
//  [241]     zero pooled + ctr
//  [242,250) full delta chain per b: xp,k,v, Gram, recurrence, u
//            (u via LDS column-tiles of Wq_d — no global transpose needed)
// ---------------------------------------------------------------------------
__global__ __launch_bounds__(192) void setup(
    const float* __restrict__ Wv_a, const float* __restrict__ Wo_a,
    const float* __restrict__ bv_a, const float* __restrict__ bo_a,
    const float* __restrict__ Wq_t,
    const float* __restrict__ x, const float* __restrict__ W_in,
    const float* __restrict__ b_in, const float* __restrict__ Wk_d,
    const float* __restrict__ Wv_d, const float* __restrict__ Wq_d,
    float* __restrict__ Wavo_ws, float* __restrict__ b_avo,
    float* __restrict__ WqtT,
    float* __restrict__ Ed_ws, float* __restrict__ Ud_ws,
    float* __restrict__ pooled, unsigned int* __restrict__ ctr)
{
    __shared__ __align__(16) float S_XR[ND][MEL];      // also Wavo row buffer
    __shared__ __align__(16) float S_XP[ND][Dd];
    __shared__ __align__(16) float S_K[ND][Dd];
    __shared__ __align__(16) float S_V[ND][Dd];
    __shared__ float S_G[16], S_MC[16];
    __shared__ float S_WT[192 * 49];                   // Wq_d column tile, padded

    int blk = blockIdx.x, tid = threadIdx.x;

    if (blk < 192) {                              // Wavo row m (k-outer coalesced)
        int m = blk;
        float* col = (float*)S_XR;
        col[tid] = Wv_a[m * Dd + tid];
        __syncthreads();
        int o = tid;
        float acc = 0.f;
        #pragma unroll 8
        for (int k = 0; k < Dd; k += 4) {
            acc += Wo_a[(k + 0) * Dd + o] * col[k + 0];
            acc += Wo_a[(k + 1) * Dd + o] * col[k + 1];
            acc += Wo_a[(k + 2) * Dd + o] * col[k + 2];
            acc += Wo_a[(k + 3) * Dd + o] * col[k + 3];
        }
        Wavo_ws[m * Dd + o] = acc;
        return;
    }
    if (blk == 192) {                             // b_avo
        int o = tid;
        float s = bo_a[o];
        #pragma unroll 4
        for (int m = 0; m < Dd; m++) s += bv_a[m] * Wo_a[m * Dd + o];
        b_avo[o] = s;
        return;
    }
    if (blk < 241) {                              // WqtT[e][o] = Wq_t[o][e]
        int r0 = 4 * (blk - 193);
        float4 v;
        v.x = Wq_t[(r0 + 0) * Dd + tid];
        v.y = Wq_t[(r0 + 1) * Dd + tid];
        v.z = Wq_t[(r0 + 2) * Dd + tid];
        v.w = Wq_t[(r0 + 3) * Dd + tid];
        *(float4*)&WqtT[tid * Dd + r0] = v;
        return;
    }
    if (blk == 241) {                             // zero pooled + counter
        for (int q = tid; q < Bb * Dd; q += 192) pooled[q] = 0.f;
        if (tid == 0) *ctr = 0u;
        return;
    }

    // ---- delta chain for batch b ----
    int b = blk - 242;
    if (tid < 128) {
        int i = tid >> 5, c = tid & 31;
        ((float4*)S_XR[i])[c] = ((const float4*)&x[((size_t)b * Tt + 64 * i) * MEL])[c];
    }
    __syncthreads();
    {                                             // xp = x @ W_in + b_in (4 rows)
        int o = tid;
        float a0 = b_in[o], a1 = a0, a2 = a0, a3 = a0;
        #pragma unroll 8
        for (int k = 0; k < MEL; k += 4) {
            float w0 = W_in[(k + 0) * Dd + o], w1 = W_in[(k + 1) * Dd + o];
            float w2 = W_in[(k + 2) * Dd + o], w3 = W_in[(k + 3) * Dd + o];
            a0 += w0 * S_XR[0][k] + w1 * S_XR[0][k + 1] + w2 * S_XR[0][k + 2] + w3 * S_XR[0][k + 3];
            a1 += w0 * S_XR[1][k] + w1 * S_XR[1][k + 1] + w2 * S_XR[1][k + 2] + w3 * S_XR[1][k + 3];
            a2 += w0 * S_XR[2][k] + w1 * S_XR[2][k + 1] + w2 * S_XR[2][k + 2] + w3 * S_XR[2][k + 3];
            a3 += w0 * S_XR[3][k] + w1 * S_XR[3][k + 1] + w2 * S_XR[3][k + 2] + w3 * S_XR[3][k + 3];
        }
        S_XP[0][o] = a0; S_XP[1][o] = a1; S_XP[2][o] = a2; S_XP[3][o] = a3;
    }
    __syncthreads();
    {                                             // k,v projections (4 rows)
        int o = tid;
        float k0 = 0, k1 = 0, k2 = 0, k3 = 0, v0 = 0, v1 = 0, v2 = 0, v3 = 0;
        #pragma unroll 4
        for (int k = 0; k < Dd; k++) {
            float wk = Wk_d[k * Dd + o], wv = Wv_d[k * Dd + o];
            float x0 = S_XP[0][k], x1 = S_XP[1][k], x2 = S_XP[2][k], x3 = S_XP[3][k];
            k0 += x0 * wk; k1 += x1 * wk; k2 += x2 * wk; k3 += x3 * wk;
            v0 += x0 * wv; v1 += x1 * wv; v2 += x2 * wv; v3 += x3 * wv;
        }
        S_K[0][o] = k0; S_K[1][o] = k1; S_K[2][o] = k2; S_K[3][o] = k3;
        S_V[0][o] = v0; S_V[1][o] = v1; S_V[2][o] = v2; S_V[3][o] = v3;
    }
    __syncthreads();
    if (tid < 16) {                               // Gram + coefficient table
        int i = tid >> 2, j = tid & 3;
        float s = 0.f;
        for (int d = 0; d < Dd; d++) s += S_K[i][d] * S_K[j][d];
        S_G[tid] = s;
        S_MC[tid] = (j <= i) ? memcoef(i, j) : 0.f;   // mc[n=i][i=j]
    }
    __syncthreads();
    {                                             // recurrence (column-private)
        for (int i = 1; i < ND; i++) {
            float acc = S_V[i][tid];
            for (int m = 0; m < i; m++)
                acc -= S_MC[(i - 1) * ND + m] * S_G[i * ND + m] * S_V[m][tid];
            S_V[i][tid] = acc;
        }
        for (int i = 0; i < ND; i++) Ed_ws[(b * ND + i) * Dd + tid] = S_V[i][tid];
    }
    // u_i = Wq_d @ k_i via 4 LDS column tiles of Wq_d (padded stride 49)
    {
        float u0 = 0.f, u1 = 0.f, u2 = 0.f, u3 = 0.f;
        for (int t = 0; t < 4; t++) {
            int e0 = t * 48;
            __syncthreads();
            for (int q = tid; q < 192 * 48; q += 192) {
                int r = q / 48, c = q - r * 48;
                S_WT[r * 49 + c] = Wq_d[r * Dd + e0 + c];
            }
            __syncthreads();
            const float* wrow = &S_WT[tid * 49];
            #pragma unroll 4
            for (int c = 0; c < 48; c++) {
                float w = wrow[c];
                u0 += w * S_K[0][e0 + c];
                u1 += w * S_K[1][e0 + c];
                u2 += w * S_K[2][e0 + c];
                u3 += w * S_K[3][e0 + c];
            }
        }
        Ud_ws[(b * ND + 0) * Dd + tid] = u0;
        Ud_ws[(b * ND + 1) * Dd + tid] = u1;
        Ud_ws[(b * ND + 2) * Dd + tid] = u2;
        Ud_ws[(b * ND + 3) * Dd + tid] = u3;
    }
}

// ---------------------------------------------------------------------------
// pipeline: grid B*128 (2 rows/block), 192 threads, k-outer coalesced weights.
// Produces x3; tiles with t0%8==0 also emit theta k/v/u~ for the update row.
// ---------------------------------------------------------------------------
__global__ __launch_bounds__(192) void pipeline(
    const float* __restrict__ x, const float* __restrict__ W_in,
    const float* __restrict__ b_in,
    const float* __restrict__ ln1_g, const float* __restrict__ ln1_b,
    const float* __restrict__ pw1_w, const float* __restrict__ pw1_b,
    const float* __restrict__ dw_w, const float* __restrict__ dw_b,
    const float* __restrict__ bn_s, const float* __restrict__ bn_b,
    const float* __restrict__ pw2_w, const float* __restrict__ pw2_b,
    const float* __restrict__ Wavo_ws, const float* __restrict__ b_avo,
    const float* __restrict__ Ed_ws, const float* __restrict__ Ud_ws,
    const float* __restrict__ Wk_t, const float* __restrict__ Wv_t,
    const float* __restrict__ WqtT,
    float* __restrict__ x3_ws, float* __restrict__ Kt_ws,
    float* __restrict__ Vt_ws, float* __restrict__ Ut_ws)
{
    int blk = blockIdx.x;
    int b = blk >> 7, tile = blk & 127;
    int t0 = tile * PT, n = tile >> 5;     // delta epoch, tile-uniform
    int tid = threadIdx.x;

    __shared__ __align__(16) float XR[PT][MEL];
    __shared__ __align__(16) float XP[PT][Dd];      // xp; later x3
    __shared__ __align__(16) float ED[ND][PADD], UD[ND][PADD];
    __shared__ __align__(16) float X1[PT][Dd], X2[PT][Dd];
    __shared__ __align__(16) float LNX[PT][Dd], HG[PT][Dd];
    __shared__ float KTs[Dd];
    __shared__ float WQs[PT * ND];
    __shared__ float mv[PT][2];

    if (tid < 64) {
        int r = tid >> 5, c = tid & 31;
        ((float4*)XR[r])[c] = ((const float4*)&x[((size_t)b * Tt + t0 + r) * MEL])[c];
    }
    for (int q = tid; q < ND * 48 * 2; q += 192) {
        int which = q >= ND * 48;
        int qq = which ? q - ND * 48 : q;
        int i = qq / 48, c = qq - i * 48;
        if (!which) ((float4*)ED[i])[c] = ((const float4*)&Ed_ws[(b * ND + i) * Dd])[c];
        else        ((float4*)UD[i])[c] = ((const float4*)&Ud_ws[(b * ND + i) * Dd])[c];
    }
    __syncthreads();

    int o = tid;
    // xp = x @ W_in + b_in   (K=128)
    {
        float acc[PT];
        float bb = b_in[o];
        #pragma unroll
        for (int r = 0; r < PT; r++) acc[r] = bb;
        #pragma unroll 8
        for (int k = 0; k < MEL; k += 4) {
            float w0 = W_in[(k + 0) * Dd + o], w1 = W_in[(k + 1) * Dd + o];
            float w2 = W_in[(k + 2) * Dd + o], w3 = W_in[(k + 3) * Dd + o];
            #pragma unroll
            for (int r = 0; r < PT; r++) {
                float4 xv = *(const float4*)&XR[r][k];
                acc[r] += w0 * xv.x + w1 * xv.y + w2 * xv.z + w3 * xv.w;
            }
        }
        #pragma unroll
        for (int r = 0; r < PT; r++) XP[r][tid] = acc[r];
    }
    __syncthreads();

    // delta dots: WQs[r][i] = (xp_r . u_i) * coef(n,i)
    if (tid < 64) {
        int r = tid >> 5, i = (tid >> 3) & 3, c = tid & 7;
        float s = 0.f;
        const float* xp = XP[r];
        const float* u = UD[i];
        #pragma unroll
        for (int j = 0; j < 24; j++) s += xp[c * 24 + j] * u[c * 24 + j];
        s += __shfl_down(s, 4, 8);
        s += __shfl_down(s, 2, 8);
        s += __shfl_down(s, 1, 8);
        if (c == 0) {
            float coef = (i <= n) ? memcoef(n, i) : 0.f;
            WQs[r * ND + i] = s * coef;
        }
    }
    __syncthreads();

    // x1 = xp + 0.5 * sum_i WQs * err_i
    {
        #pragma unroll
        for (int r = 0; r < PT; r++) {
            float dout = WQs[r * ND + 0] * ED[0][tid] + WQs[r * ND + 1] * ED[1][tid]
                       + WQs[r * ND + 2] * ED[2][tid] + WQs[r * ND + 3] * ED[3][tid];
            X1[r][tid] = XP[r][tid] + 0.5f * dout;
        }
    }
    __syncthreads();

    // x2 = x1 + x1 @ Wavo + b_avo   (K=192)
    {
        float acc[PT];
        float bb = b_avo[o];
        #pragma unroll
        for (int r = 0; r < PT; r++) acc[r] = bb;
        #pragma unroll 8
        for (int k = 0; k < Dd; k += 4) {
            float w0 = Wavo_ws[(k + 0) * Dd + o], w1 = Wavo_ws[(k + 1) * Dd + o];
            float w2 = Wavo_ws[(k + 2) * Dd + o], w3 = Wavo_ws[(k + 3) * Dd + o];
            #pragma unroll
            for (int r = 0; r < PT; r++) {
                float4 xv = *(const float4*)&X1[r][k];
                acc[r] += w0 * xv.x + w1 * xv.y + w2 * xv.z + w3 * xv.w;
            }
        }
        #pragma unroll
        for (int r = 0; r < PT; r++) X2[r][tid] = X1[r][tid] + acc[r];
    }
    __syncthreads();

    // LN1 stats (2 groups of 32 lanes)
    if (tid < 64) {
        int r = tid >> 5, j = tid & 31;
        float s = 0.f, sq = 0.f;
        for (int d = j; d < Dd; d += 32) { float v = X2[r][d]; s += v; sq += v * v; }
        for (int off = 16; off > 0; off >>= 1) {
            s += __shfl_down(s, off, 32); sq += __shfl_down(sq, off, 32);
        }
        if (j == 0) {
            float mean = s / Dd;
            mv[r][0] = mean;
            mv[r][1] = rsqrtf(sq / Dd - mean * mean + EPSc);
        }
    }
    __syncthreads();
    {
        float g = ln1_g[tid], bb = ln1_b[tid];
        #pragma unroll
        for (int r = 0; r < PT; r++)
            LNX[r][tid] = (X2[r][tid] - mv[r][0]) * mv[r][1] * g + bb;
    }
    __syncthreads();

    // pw1 (dual halves) + GLU + dw + bn + silu   (K=192, 2 outputs)
    {
        float aa[PT], gg[PT];
        float ba = pw1_b[o], bg = pw1_b[o + Dd];
        #pragma unroll
        for (int r = 0; r < PT; r++) { aa[r] = ba; gg[r] = bg; }
        #pragma unroll 4
        for (int k = 0; k < Dd; k += 4) {
            float wa0 = pw1_w[(k + 0) * 2 * Dd + o], wg0 = pw1_w[(k + 0) * 2 * Dd + Dd + o];
            float wa1 = pw1_w[(k + 1) * 2 * Dd + o], wg1 = pw1_w[(k + 1) * 2 * Dd + Dd + o];
            float wa2 = pw1_w[(k + 2) * 2 * Dd + o], wg2 = pw1_w[(k + 2) * 2 * Dd + Dd + o];
            float wa3 = pw1_w[(k + 3) * 2 * Dd + o], wg3 = pw1_w[(k + 3) * 2 * Dd + Dd + o];
            #pragma unroll
            for (int r = 0; r < PT; r++) {
                float4 xv = *(const float4*)&LNX[r][k];
                aa[r] += wa0 * xv.x + wa1 * xv.y + wa2 * xv.z + wa3 * xv.w;
                gg[r] += wg0 * xv.x + wg1 * xv.y + wg2 * xv.z + wg3 * xv.w;
            }
        }
        float dww = dw_w[o], dwb = dw_b[o], bns = bn_s[o], bnb = bn_b[o];
        #pragma unroll
        for (int r = 0; r < PT; r++) {
            float h = aa[r] * sigmoidf_(gg[r]);
            h = h * dww + dwb;
            h = h * bns + bnb;
            h = h * sigmoidf_(h);
            HG[r][tid] = h;
        }
    }
    __syncthreads();

    // pw2 + residual -> x3 (store + keep in XP)
    {
        float acc[PT];
        float bb = pw2_b[o];
        #pragma unroll
        for (int r = 0; r < PT; r++) acc[r] = bb;
        #pragma unroll 8
        for (int k = 0; k < Dd; k += 4) {
            float w0 = pw2_w[(k + 0) * Dd + o], w1 = pw2_w[(k + 1) * Dd + o];
            float w2 = pw2_w[(k + 2) * Dd + o], w3 = pw2_w[(k + 3) * Dd + o];
            #pragma unroll
            for (int r = 0; r < PT; r++) {
                float4 xv = *(const float4*)&HG[r][k];
                acc[r] += w0 * xv.x + w1 * xv.y + w2 * xv.z + w3 * xv.w;
            }
        }
        #pragma unroll
        for (int r = 0; r < PT; r++) {
            float v = X2[r][tid] + acc[r];
            XP[r][tid] = v;
            x3_ws[((size_t)b * Tt + t0 + r) * Dd + tid] = v;
        }
    }

    // theta k/v/u~ for update row (t0%8==0 <=> tile%4==0; row 0) — block-uniform
    if ((tile & 3) == 0) {
        int i8 = tile >> 2;
        __syncthreads();
        {
            float ak = 0.f, av = 0.f;
            #pragma unroll 4
            for (int k = 0; k < Dd; k += 4) {
                float x0 = XP[0][k + 0], x1v = XP[0][k + 1];
                float x2v = XP[0][k + 2], x3v = XP[0][k + 3];
                ak += Wk_t[(k + 0) * Dd + o] * x0 + Wk_t[(k + 1) * Dd + o] * x1v
                    + Wk_t[(k + 2) * Dd + o] * x2v + Wk_t[(k + 3) * Dd + o] * x3v;
                av += Wv_t[(k + 0) * Dd + o] * x0 + Wv_t[(k + 1) * Dd + o] * x1v
                    + Wv_t[(k + 2) * Dd + o] * x2v + Wv_t[(k + 3) * Dd + o] * x3v;
            }
            Kt_ws[(b * NT + i8) * Dd + o] = ak;
            Vt_ws[(b * NT + i8) * Dd + o] = av;
            KTs[o] = ak;
        }
        __syncthreads();
        {
            float au = 0.f;
            #pragma unroll 8
            for (int k = 0; k < Dd; k += 4) {
                au += WqtT[(k + 0) * Dd + o] * KTs[k + 0]
                    + WqtT[(k + 1) * Dd + o] * KTs[k + 1]
                    + WqtT[(k + 2) * Dd + o] * KTs[k + 2]
                    + WqtT[(k + 3) * Dd + o] * KTs[k + 3];
            }
            Ut_ws[(b * NT + i8) * Dd + o] = au;
        }
    }
}

// ---------------------------------------------------------------------------
// theta_solve: grid B = 8, 192 threads. T-matrix formulation:
// S[i][m] = mc[i-1][m]*G[i][m]; T = (I+S)^{-1} (32 independent column solves);
// err = T @ V (parallel). Writes err into Et_ws.
// ---------------------------------------------------------------------------
__global__ __launch_bounds__(192) void theta_solve(
    const float* __restrict__ Kt_ws, const float* __restrict__ Vt_ws,
    float* __restrict__ Et_ws)
{
    int b = blockIdx.x, tid = threadIdx.x;
    __shared__ __align__(16) float K[NT][PADD], V[NT][PADD];
    __shared__ float G[NT * NT], mcc[NT * NT];
    __shared__ float T[NT * 33];

    for (int q = tid; q < NT * 48; q += 192) {
        int i = q / 48, c = q - i * 48;
        ((float4*)K[i])[c] = ((const float4*)&Kt_ws[(b * NT + i) * Dd])[c];
        ((float4*)V[i])[c] = ((const float4*)&Vt_ws[(b * NT + i) * Dd])[c];
    }
    if (tid < NT) {
        int i = tid;
        float m = 0.f, pw = LRc;
        for (int nn = 0; nn < NT; nn++) {
            float v;
            if (nn < i) v = 0.f;
            else if (nn == i) { m = LRc; v = m; }
            else { pw *= ETAc; m = MDEC * m + pw; v = m; }
            mcc[nn * NT + i] = v;
        }
    }
    __syncthreads();
    for (int p = tid; p < NT * NT; p += 192) {       // Gram
        int i = p >> 5, j = p & 31;
        const float4* ki = (const float4*)K[i];
        const float4* kj = (const float4*)K[j];
        float s = 0.f;
        #pragma unroll 4
        for (int kk = 0; kk < 48; kk++) s += dot4(ki[kk], kj[kk]);
        G[p] = s;
    }
    __syncthreads();
    for (int p = tid; p < NT * NT; p += 192) {       // S in place over G
        int i = p >> 5, m = p & 31;
        G[p] = (m < i) ? mcc[(i - 1) * NT + m] * G[p] : 0.f;
    }
    __syncthreads();
    if (tid < NT) {                                   // T column solve (indep per col)
        int j = tid;
        T[j * 33 + j] = 1.f;
        for (int i = j + 1; i < NT; i++) {
            float s = 0.f;
            for (int m = j; m < i; m++) s += G[i * NT + m] * T[m * 33 + j];
            T[i * 33 + j] = -s;
        }
    }
    __syncthreads();
    {                                                 // err = T @ V (col-private)
        for (int i = 0; i < NT; i++) {
            float s = 0.f;
            for (int j = 0; j <= i; j++) s += T[i * 33 + j] * V[j][tid];
            Et_ws[(b * NT + i) * Dd + tid] = s;
        }
    }
}

// ---------------------------------------------------------------------------
// retrieve: grid B*32 (8 rows/block), 256 threads + fused head (last block).
// ---------------------------------------------------------------------------
__global__ __launch_bounds__(256) void retrieve(
    const float* __restrict__ x3_ws, const float* __restrict__ Ut_ws,
    const float* __restrict__ Et_ws, const float* __restrict__ ln2_g,
    const float* __restrict__ ln2_b, float* __restrict__ pooled,
    const float* __restrict__ Wc, const float* __restrict__ bc,
    float* __restrict__ out, unsigned int* __restrict__ ctr)
{
    int blk = blockIdx.x, b = blk >> 5, tile = blk & 31;
    int t0 = tile * RTT, n = tile;
    int tid = threadIdx.x;

    __shared__ __align__(16) float UT[NT][PADD];
    __shared__ __align__(16) float XS[RTT][PADD];
    __shared__ float WQ[RTT * NT];
    __shared__ float mv[RTT][2];
    __shared__ float PLD[Bb * Dd];
    __shared__ bool isLast;

    for (int q = tid; q < NT * 48; q += 256) {
        int i = q / 48, c = q - i * 48;
        ((float4*)UT[i])[c] = ((const float4*)&Ut_ws[(b * NT + i) * Dd])[c];
    }
    for (int q = tid; q < RTT * 48; q += 256) {
        int r = q / 48, c = q - r * 48;
        ((float4*)XS[r])[c] = ((const float4*)&x3_ws[((size_t)b * Tt + t0 + r) * Dd])[c];
    }
    __syncthreads();

    // dots: tid = r*32 + i ; w[r][i] = (x3_r . u~_i) * coef
    {
        int r = tid >> 5, i = tid & 31;
        const float4* u4 = (const float4*)UT[i];
        const float4* x4 = (const float4*)XS[r];
        float s = 0.f;
        #pragma unroll 8
        for (int kk = 0; kk < 48; kk++) s += dot4(u4[kk], x4[kk]);
        float coef = (i <= n) ? memcoef(n, i) : 0.f;
        WQ[tid] = s * coef;
    }
    __syncthreads();

    // x4 = x3 + 0.5 * sum_i WQ * err_i
    if (tid < Dd) {
        float acc[RTT] = {};
        #pragma unroll 4
        for (int i = 0; i < NT; i++) {
            float e = Et_ws[(b * NT + i) * Dd + tid];
            #pragma unroll
            for (int r = 0; r < RTT; r++) acc[r] += WQ[r * NT + i] * e;
        }
        #pragma unroll
        for (int r = 0; r < RTT; r++) XS[r][tid] += 0.5f * acc[r];
    }
    __syncthreads();

    // LN2 stats
    {
        int r = tid >> 5, j = tid & 31;
        float s = 0.f, sq = 0.f;
        for (int d = j; d < Dd; d += 32) { float v = XS[r][d]; s += v; sq += v * v; }
        for (int off = 16; off > 0; off >>= 1) {
            s += __shfl_down(s, off, 32); sq += __shfl_down(sq, off, 32);
        }
        if (j == 0) {
            float mean = s / Dd;
            mv[r][0] = mean;
            mv[r][1] = rsqrtf(sq / Dd - mean * mean + EPSc);
        }
    }
    __syncthreads();

    if (tid < Dd) {
        float g = ln2_g[tid], bb = ln2_b[tid];
        float sum = 0.f;
        #pragma unroll
        for (int r = 0; r < RTT; r++)
            sum += (XS[r][tid] - mv[r][0]) * mv[r][1] * g + bb;
        atomicAdd(&pooled[b * Dd + tid], sum);
    }

    // -------- fused head: last block computes out = (pooled/T)@Wc + bc -----
    __threadfence();
    if (tid == 0) {
        unsigned int old = atomicAdd(ctr, 1u);
        isLast = (old == (unsigned)(Bb * 32 - 1));
    }
    __syncthreads();
    if (isLast) {
        __threadfence();
        for (int q = tid; q < Bb * Dd; q += 256)
            PLD[q] = *(volatile const float*)&pooled[q];
        __syncthreads();
        if (tid < Bb * NCc) {
            int bo = tid / NCc, c = tid - bo * NCc;
            float s = 0.f;
            for (int d = 0; d < Dd; d++) s += PLD[bo * Dd + d] * Wc[d * NCc + c];
            out[tid] = s * (1.0f / Tt) + bc[c];
        }
    }
}

extern "C" void kernel_launch(void* const* d_in, const int* in_sizes, int n_in,
                              void* d_out, int out_size, void* d_ws, size_t ws_size,
                              hipStream_t stream) {
    const float* x     = (const float*)d_in[0];
    const float* W_in  = (const float*)d_in[1];
    const float* b_in  = (const float*)d_in[2];
    const float* Wv_a  = (const float*)d_in[3];
    const float* bv_a  = (const float*)d_in[4];
    const float* Wo_a  = (const float*)d_in[5];
    const float* bo_a  = (const float*)d_in[6];
    const float* ln1_g = (const float*)d_in[7];
    const float* ln1_b = (const float*)d_in[8];
    const float* pw1_w = (const float*)d_in[9];
    const float* pw1_b = (const float*)d_in[10];
    const float* dw_w  = (const float*)d_in[11];
    const float* dw_b  = (const float*)d_in[12];
    const float* bn_s  = (const float*)d_in[13];
    const float* bn_b  = (const float*)d_in[14];
    const float* pw2_w = (const float*)d_in[15];
    const float* pw2_b = (const float*)d_in[16];
    const float* Wk_t  = (const float*)d_in[17];
    const float* Wv_t  = (const float*)d_in[18];
    const float* Wq_t  = (const float*)d_in[19];
    const float* Wk_d  = (const float*)d_in[20];
    const float* Wv_d  = (const float*)d_in[21];
    const float* Wq_d  = (const float*)d_in[22];
    const float* ln2_g = (const float*)d_in[23];
    const float* ln2_b = (const float*)d_in[24];
    const float* Wc    = (const float*)d_in[25];
    const float* bc    = (const float*)d_in[26];

    float* ws = (float*)d_ws;
    size_t off = 0;
    float* x3_ws   = ws + off; off += (size_t)Bb * Tt * Dd;
    float* Ed_ws   = ws + off; off += Bb * ND * Dd;   // delta err
    float* Ud_ws   = ws + off; off += Bb * ND * Dd;
    float* Kt_ws   = ws + off; off += Bb * NT * Dd;
    float* Vt_ws   = ws + off; off += Bb * NT * Dd;
    float* Et_ws   = ws + off; off += Bb * NT * Dd;   // theta err
    float* Ut_ws   = ws + off; off += Bb * NT * Dd;
    float* pooled  = ws + off; off += Bb * Dd;
    float* Wavo_ws = ws + off; off += Dd * Dd;
    float* WqtT    = ws + off; off += Dd * Dd;
    float* b_avo   = ws + off; off += Dd;
    unsigned int* ctr = (unsigned int*)(ws + off); off += 1;

    setup<<<250, 192, 0, stream>>>(
        Wv_a, Wo_a, bv_a, bo_a, Wq_t,
        x, W_in, b_in, Wk_d, Wv_d, Wq_d,
        Wavo_ws, b_avo, WqtT, Ed_ws, Ud_ws, pooled, ctr);
    pipeline<<<Bb * 128, 192, 0, stream>>>(
        x, W_in, b_in, ln1_g, ln1_b, pw1_w, pw1_b, dw_w, dw_b,
        bn_s, bn_b, pw2_w, pw2_b, Wavo_ws, b_avo, Ed_ws, Ud_ws,
        Wk_t, Wv_t, WqtT, x3_ws, Kt_ws, Vt_ws, Ut_ws);
    theta_solve<<<Bb, 192, 0, stream>>>(Kt_ws, Vt_ws, Et_ws);
    retrieve<<<Bb * 32, 256, 0, stream>>>(
        x3_ws, Ut_ws, Et_ws, ln2_g, ln2_b, pooled, Wc, bc, (float*)d_out, ctr);
}

// Round 7
// 224.653 us; speedup vs baseline: 1.1560x; 1.1560x over previous
//
#include <hip/hip_runtime.h>
#include <math.h>

#define Bb 8
#define Tt 256
#define MEL 128
#define Dd 192
#define NCc 20
#define ND 4                  // delta ranks (updates at t%64==0)
#define NT 32                 // theta ranks (updates at t%8==0)
#define ETAc 0.9f
#define LRc 0.1f
#define MDEC 0.99f            // 1 - ALPHA
#define EPSc 1e-5f
#define PT 4                  // pipeline rows per block
#define RTT 8                 // retrieve rows per block
#define PADD 196              // padded LDS row for float4 access
#define UPAD 193              // odd pad -> conflict-free lane-varying rows

__device__ __forceinline__ float sigmoidf_(float x) {
    return 1.0f / (1.0f + __expf(-x));
}

// coefficient of (k_i err_i^T) in M_n, valid for i<=n
__device__ __forceinline__ float memcoef(int n, int i) {
    float m = LRc, pw = LRc;
    for (int nn = i + 1; nn <= n; nn++) { pw *= ETAc; m = MDEC * m + pw; }
    return m;
}

__device__ __forceinline__ float dot4(float4 a, float4 b) {
    return a.x * b.x + a.y * b.y + a.z * b.z + a.w * b.w;
}

// ---------------------------------------------------------------------------
// setup: grid 322 x 192 — everything wide & coalesced.
//  [0,192)   Wavo row m = Wv_a[m,:] @ Wo_a (k-outer)
//  [192]     b_avo
//  [193,241) WqtT transpose (4 rows each)
//  [241,289) WqdT transpose (4 rows each)
//  [289]     zero pooled + ctr
//  [290,322) delta k/v for (b,i): xp -> k,v
// ---------------------------------------------------------------------------
__global__ __launch_bounds__(192) void setup(
    const float* __restrict__ Wv_a, const float* __restrict__ Wo_a,
    const float* __restrict__ bv_a, const float* __restrict__ bo_a,
    const float* __restrict__ Wq_t, const float* __restrict__ Wq_d,
    const float* __restrict__ x, const float* __restrict__ W_in,
    const float* __restrict__ b_in, const float* __restrict__ Wk_d,
    const float* __restrict__ Wv_d,
    float* __restrict__ Wavo_ws, float* __restrict__ b_avo,
    float* __restrict__ WqtT, float* __restrict__ WqdT,
    float* __restrict__ Kd_ws, float* __restrict__ Vd_ws,
    float* __restrict__ pooled, unsigned int* __restrict__ ctr)
{
    __shared__ __align__(16) float smem[512];
    int blk = blockIdx.x, tid = threadIdx.x;

    if (blk < 192) {                              // Wavo row m (k-outer coalesced)
        int m = blk;
        smem[tid] = Wv_a[m * Dd + tid];
        __syncthreads();
        int o = tid;
        float acc = 0.f;
        #pragma unroll 8
        for (int k = 0; k < Dd; k += 4) {
            acc += Wo_a[(k + 0) * Dd + o] * smem[k + 0];
            acc += Wo_a[(k + 1) * Dd + o] * smem[k + 1];
            acc += Wo_a[(k + 2) * Dd + o] * smem[k + 2];
            acc += Wo_a[(k + 3) * Dd + o] * smem[k + 3];
        }
        Wavo_ws[m * Dd + o] = acc;
        return;
    }
    if (blk == 192) {                             // b_avo
        int o = tid;
        float s = bo_a[o];
        #pragma unroll 4
        for (int m = 0; m < Dd; m++) s += bv_a[m] * Wo_a[m * Dd + o];
        b_avo[o] = s;
        return;
    }
    if (blk < 241) {                              // WqtT[e][o] = Wq_t[o][e]
        int r0 = 4 * (blk - 193);
        float4 v;
        v.x = Wq_t[(r0 + 0) * Dd + tid];
        v.y = Wq_t[(r0 + 1) * Dd + tid];
        v.z = Wq_t[(r0 + 2) * Dd + tid];
        v.w = Wq_t[(r0 + 3) * Dd + tid];
        *(float4*)&WqtT[tid * Dd + r0] = v;
        return;
    }
    if (blk < 289) {                              // WqdT[e][o] = Wq_d[o][e]
        int r0 = 4 * (blk - 241);
        float4 v;
        v.x = Wq_d[(r0 + 0) * Dd + tid];
        v.y = Wq_d[(r0 + 1) * Dd + tid];
        v.z = Wq_d[(r0 + 2) * Dd + tid];
        v.w = Wq_d[(r0 + 3) * Dd + tid];
        *(float4*)&WqdT[tid * Dd + r0] = v;
        return;
    }
    if (blk == 289) {                             // zero pooled + counter
        for (int q = tid; q < Bb * Dd; q += 192) pooled[q] = 0.f;
        if (tid == 0) *ctr = 0u;
        return;
    }

    // ---- delta k/v for (b,i) ----
    int q = blk - 290;
    int b = q >> 2, i = q & 3;
    float* XR = smem;              // [128]
    float* XP = smem + 128;        // [192]
    if (tid < 128) XR[tid] = x[((size_t)b * Tt + 64 * i) * MEL + tid];
    __syncthreads();
    {
        int o = tid;
        float acc = b_in[o];
        #pragma unroll 8
        for (int k = 0; k < MEL; k += 4) {
            acc += W_in[(k + 0) * Dd + o] * XR[k + 0];
            acc += W_in[(k + 1) * Dd + o] * XR[k + 1];
            acc += W_in[(k + 2) * Dd + o] * XR[k + 2];
            acc += W_in[(k + 3) * Dd + o] * XR[k + 3];
        }
        XP[o] = acc;
    }
    __syncthreads();
    {
        int o = tid;
        float ak = 0.f, av = 0.f;
        #pragma unroll 4
        for (int k = 0; k < Dd; k += 4) {
            float x0 = XP[k + 0], x1 = XP[k + 1], x2 = XP[k + 2], x3 = XP[k + 3];
            ak += Wk_d[(k + 0) * Dd + o] * x0 + Wk_d[(k + 1) * Dd + o] * x1
                + Wk_d[(k + 2) * Dd + o] * x2 + Wk_d[(k + 3) * Dd + o] * x3;
            av += Wv_d[(k + 0) * Dd + o] * x0 + Wv_d[(k + 1) * Dd + o] * x1
                + Wv_d[(k + 2) * Dd + o] * x2 + Wv_d[(k + 3) * Dd + o] * x3;
        }
        Kd_ws[(b * ND + i) * Dd + o] = ak;
        Vd_ws[(b * ND + i) * Dd + o] = av;
    }
}

// ---------------------------------------------------------------------------
// delta_solve: grid B*5 = 40.
//  role 0: Gram 4x4 + 3-step err recurrence, rewrites Vd_ws in place (-> err)
//  roles 1..4: u_i = Wq_d @ k_i via WqdT (k-outer coalesced)
// ---------------------------------------------------------------------------
__global__ __launch_bounds__(192) void delta_solve(
    const float* __restrict__ WqdT, const float* __restrict__ Kd_ws,
    float* __restrict__ Vd_ws, float* __restrict__ Ud_ws)
{
    int blk = blockIdx.x, b = blk / 5, role = blk % 5, tid = threadIdx.x;
    if (role == 0) {
        __shared__ __align__(16) float K4[ND][Dd], V4[ND][Dd];
        __shared__ float G[16], mc[16];
        for (int q = tid; q < ND * 48; q += 192) {
            int i = q / 48, c = q - i * 48;
            ((float4*)K4[i])[c] = ((const float4*)&Kd_ws[(b * ND + i) * Dd])[c];
            ((float4*)V4[i])[c] = ((const float4*)&Vd_ws[(b * ND + i) * Dd])[c];
        }
        __syncthreads();
        if (tid < 16) {
            int i = tid >> 2, j = tid & 3;
            float s = 0.f;
            for (int d = 0; d < Dd; d++) s += K4[i][d] * K4[j][d];
            G[tid] = s;
            mc[tid] = (j <= i) ? memcoef(i, j) : 0.f;   // mc[n=i][i=j]
        }
        __syncthreads();
        for (int i = 1; i < ND; i++) {       // column-private recurrence
            float acc = V4[i][tid];
            for (int m = 0; m < i; m++)
                acc -= mc[(i - 1) * ND + m] * G[i * ND + m] * V4[m][tid];
            V4[i][tid] = acc;
        }
        for (int i = 0; i < ND; i++) Vd_ws[(b * ND + i) * Dd + tid] = V4[i][tid];
    } else {
        __shared__ float KS[Dd];
        int i = role - 1;
        KS[tid] = Kd_ws[(b * ND + i) * Dd + tid];
        __syncthreads();
        int o = tid;
        float acc = 0.f;
        #pragma unroll 8
        for (int k = 0; k < Dd; k += 4) {
            acc += WqdT[(k + 0) * Dd + o] * KS[k + 0];
            acc += WqdT[(k + 1) * Dd + o] * KS[k + 1];
            acc += WqdT[(k + 2) * Dd + o] * KS[k + 2];
            acc += WqdT[(k + 3) * Dd + o] * KS[k + 3];
        }
        Ud_ws[(b * ND + i) * Dd + o] = acc;
    }
}

// ---------------------------------------------------------------------------
// pipeline: grid B*64 (4 rows/block), 192 threads (R4 verified body).
// Even tiles also emit theta k/v/u~ for the t%8==0 update row (row 0).
// ---------------------------------------------------------------------------
__global__ __launch_bounds__(192) void pipeline(
    const float* __restrict__ x, const float* __restrict__ W_in,
    const float* __restrict__ b_in,
    const float* __restrict__ ln1_g, const float* __restrict__ ln1_b,
    const float* __restrict__ pw1_w, const float* __restrict__ pw1_b,
    const float* __restrict__ dw_w, const float* __restrict__ dw_b,
    const float* __restrict__ bn_s, const float* __restrict__ bn_b,
    const float* __restrict__ pw2_w, const float* __restrict__ pw2_b,
    const float* __restrict__ Wavo_ws, const float* __restrict__ b_avo,
    const float* __restrict__ Ed_ws, const float* __restrict__ Ud_ws,
    const float* __restrict__ Wk_t, const float* __restrict__ Wv_t,
    const float* __restrict__ WqtT,
    float* __restrict__ x3_ws, float* __restrict__ Kt_ws,
    float* __restrict__ Vt_ws, float* __restrict__ Ut_ws)
{
    int blk = blockIdx.x;
    int b = blk >> 6, tile = blk & 63;
    int t0 = tile * PT, n = tile >> 4;     // delta epoch, tile-uniform
    int tid = threadIdx.x;

    __shared__ __align__(16) float XR[PT][MEL];
    __shared__ __align__(16) float XP[PT][Dd];
    __shared__ __align__(16) float ED[ND][PADD], UD[ND][PADD];
    __shared__ __align__(16) float X1[PT][Dd], X2[PT][Dd];
    __shared__ __align__(16) float LNX[PT][Dd], HG[PT][Dd];
    __shared__ float X3row[Dd];
    __shared__ float KTs[Dd];
    __shared__ float WQs[PT * ND];
    __shared__ float mv[PT][2];

    if (tid < 128) {
        int r = tid >> 5, c = tid & 31;
        ((float4*)XR[r])[c] = ((const float4*)&x[((size_t)b * Tt + t0 + r) * MEL])[c];
    }
    for (int q = tid; q < ND * 48 * 2; q += 192) {
        int which = q >= ND * 48;
        int qq = which ? q - ND * 48 : q;
        int i = qq / 48, c = qq - i * 48;
        if (!which) ((float4*)ED[i])[c] = ((const float4*)&Ed_ws[(b * ND + i) * Dd])[c];
        else        ((float4*)UD[i])[c] = ((const float4*)&Ud_ws[(b * ND + i) * Dd])[c];
    }
    __syncthreads();

    int o = tid;
    // xp = x @ W_in + b_in   (K=128)
    {
        float acc[PT];
        float bb = b_in[o];
        #pragma unroll
        for (int r = 0; r < PT; r++) acc[r] = bb;
        #pragma unroll 8
        for (int k = 0; k < MEL; k += 4) {
            float w0 = W_in[(k + 0) * Dd + o], w1 = W_in[(k + 1) * Dd + o];
            float w2 = W_in[(k + 2) * Dd + o], w3 = W_in[(k + 3) * Dd + o];
            #pragma unroll
            for (int r = 0; r < PT; r++) {
                float4 xv = *(const float4*)&XR[r][k];
                acc[r] += w0 * xv.x + w1 * xv.y + w2 * xv.z + w3 * xv.w;
            }
        }
        #pragma unroll
        for (int r = 0; r < PT; r++) XP[r][tid] = acc[r];
    }
    __syncthreads();

    // delta dots: WQs[r][i] = (xp_r . u_i) * coef(n,i)
    if (tid < 128) {
        int r = tid >> 5, i = (tid >> 3) & 3, c = tid & 7;
        float s = 0.f;
        const float* xp = XP[r];
        const float* u = UD[i];
        #pragma unroll
        for (int j = 0; j < 24; j++) s += xp[c * 24 + j] * u[c * 24 + j];
        s += __shfl_down(s, 4, 8);
        s += __shfl_down(s, 2, 8);
        s += __shfl_down(s, 1, 8);
        if (c == 0) {
            float coef = (i <= n) ? memcoef(n, i) : 0.f;
            WQs[r * ND + i] = s * coef;
        }
    }
    __syncthreads();

    // x1 = xp + 0.5 * sum_i WQs * err_i
    {
        #pragma unroll
        for (int r = 0; r < PT; r++) {
            float dout = WQs[r * ND + 0] * ED[0][tid] + WQs[r * ND + 1] * ED[1][tid]
                       + WQs[r * ND + 2] * ED[2][tid] + WQs[r * ND + 3] * ED[3][tid];
            X1[r][tid] = XP[r][tid] + 0.5f * dout;
        }
    }
    __syncthreads();

    // x2 = x1 + x1 @ Wavo + b_avo   (K=192)
    {
        float acc[PT];
        float bb = b_avo[o];
        #pragma unroll
        for (int r = 0; r < PT; r++) acc[r] = bb;
        #pragma unroll 8
        for (int k = 0; k < Dd; k += 4) {
            float w0 = Wavo_ws[(k + 0) * Dd + o], w1 = Wavo_ws[(k + 1) * Dd + o];
            float w2 = Wavo_ws[(k + 2) * Dd + o], w3 = Wavo_ws[(k + 3) * Dd + o];
            #pragma unroll
            for (int r = 0; r < PT; r++) {
                float4 xv = *(const float4*)&X1[r][k];
                acc[r] += w0 * xv.x + w1 * xv.y + w2 * xv.z + w3 * xv.w;
            }
        }
        #pragma unroll
        for (int r = 0; r < PT; r++) X2[r][tid] = X1[r][tid] + acc[r];
    }
    __syncthreads();

    // LN1 stats (4 groups of 32 lanes)
    if (tid < 128) {
        int r = tid >> 5, j = tid & 31;
        float s = 0.f, sq = 0.f;
        for (int d = j; d < Dd; d += 32) { float v = X2[r][d]; s += v; sq += v * v; }
        for (int off = 16; off > 0; off >>= 1) {
            s += __shfl_down(s, off, 32); sq += __shfl_down(sq, off, 32);
        }
        if (j == 0) {
            float mean = s / Dd;
            mv[r][0] = mean;
            mv[r][1] = rsqrtf(sq / Dd - mean * mean + EPSc);
        }
    }
    __syncthreads();
    {
        float g = ln1_g[tid], bb = ln1_b[tid];
        #pragma unroll
        for (int r = 0; r < PT; r++)
            LNX[r][tid] = (X2[r][tid] - mv[r][0]) * mv[r][1] * g + bb;
    }
    __syncthreads();

    // pw1 (dual halves) + GLU + dw + bn + silu   (K=192, 2 outputs)
    {
        float aa[PT], gg[PT];
        float ba = pw1_b[o], bg = pw1_b[o + Dd];
        #pragma unroll
        for (int r = 0; r < PT; r++) { aa[r] = ba; gg[r] = bg; }
        #pragma unroll 4
        for (int k = 0; k < Dd; k += 4) {
            float wa0 = pw1_w[(k + 0) * 2 * Dd + o], wg0 = pw1_w[(k + 0) * 2 * Dd + Dd + o];
            float wa1 = pw1_w[(k + 1) * 2 * Dd + o], wg1 = pw1_w[(k + 1) * 2 * Dd + Dd + o];
            float wa2 = pw1_w[(k + 2) * 2 * Dd + o], wg2 = pw1_w[(k + 2) * 2 * Dd + Dd + o];
            float wa3 = pw1_w[(k + 3) * 2 * Dd + o], wg3 = pw1_w[(k + 3) * 2 * Dd + Dd + o];
            #pragma unroll
            for (int r = 0; r < PT; r++) {
                float4 xv = *(const float4*)&LNX[r][k];
                aa[r] += wa0 * xv.x + wa1 * xv.y + wa2 * xv.z + wa3 * xv.w;
                gg[r] += wg0 * xv.x + wg1 * xv.y + wg2 * xv.z + wg3 * xv.w;
            }
        }
        float dww = dw_w[o], dwb = dw_b[o], bns = bn_s[o], bnb = bn_b[o];
        #pragma unroll
        for (int r = 0; r < PT; r++) {
            float h = aa[r] * sigmoidf_(gg[r]);
            h = h * dww + dwb;
            h = h * bns + bnb;
            h = h * sigmoidf_(h);
            HG[r][tid] = h;
        }
    }
    __syncthreads();

    // pw2 + residual -> x3 (direct store; row 0 kept in LDS for theta)
    {
        float acc[PT];
        float bb = pw2_b[o];
        #pragma unroll
        for (int r = 0; r < PT; r++) acc[r] = bb;
        #pragma unroll 8
        for (int k = 0; k < Dd; k += 4) {
            float w0 = pw2_w[(k + 0) * Dd + o], w1 = pw2_w[(k + 1) * Dd + o];
            float w2 = pw2_w[(k + 2) * Dd + o], w3 = pw2_w[(k + 3) * Dd + o];
            #pragma unroll
            for (int r = 0; r < PT; r++) {
                float4 xv = *(const float4*)&HG[r][k];
                acc[r] += w0 * xv.x + w1 * xv.y + w2 * xv.z + w3 * xv.w;
            }
        }
        #pragma unroll
        for (int r = 0; r < PT; r++) {
            float v = X2[r][tid] + acc[r];
            if (r == 0) X3row[tid] = v;
            x3_ws[((size_t)b * Tt + t0 + r) * Dd + tid] = v;
        }
    }

    // theta k/v/u~ for update row (t0%8==0 <=> tile even; row 0)
    if ((tile & 1) == 0) {
        int i8 = tile >> 1;
        __syncthreads();
        {
            float ak = 0.f, av = 0.f;
            #pragma unroll 4
            for (int k = 0; k < Dd; k += 4) {
                float x0 = X3row[k + 0], x1v = X3row[k + 1];
                float x2v = X3row[k + 2], x3v = X3row[k + 3];
                ak += Wk_t[(k + 0) * Dd + o] * x0 + Wk_t[(k + 1) * Dd + o] * x1v
                    + Wk_t[(k + 2) * Dd + o] * x2v + Wk_t[(k + 3) * Dd + o] * x3v;
                av += Wv_t[(k + 0) * Dd + o] * x0 + Wv_t[(k + 1) * Dd + o] * x1v
                    + Wv_t[(k + 2) * Dd + o] * x2v + Wv_t[(k + 3) * Dd + o] * x3v;
            }
            Kt_ws[(b * NT + i8) * Dd + o] = ak;
            Vt_ws[(b * NT + i8) * Dd + o] = av;
            KTs[o] = ak;
        }
        __syncthreads();
        {
            float au = 0.f;
            #pragma unroll 8
            for (int k = 0; k < Dd; k += 4) {
                au += WqtT[(k + 0) * Dd + o] * KTs[k + 0]
                    + WqtT[(k + 1) * Dd + o] * KTs[k + 1]
                    + WqtT[(k + 2) * Dd + o] * KTs[k + 2]
                    + WqtT[(k + 3) * Dd + o] * KTs[k + 3];
            }
            Ut_ws[(b * NT + i8) * Dd + o] = au;
        }
    }
}

// ---------------------------------------------------------------------------
// theta_solve: grid B = 8, 192 threads. T-matrix formulation (R6 verified).
// ---------------------------------------------------------------------------
__global__ __launch_bounds__(192) void theta_solve(
    const float* __restrict__ Kt_ws, const float* __restrict__ Vt_ws,
    float* __restrict__ Et_ws)
{
    int b = blockIdx.x, tid = threadIdx.x;
    __shared__ __align__(16) float K[NT][PADD], V[NT][PADD];
    __shared__ float G[NT * NT], mcc[NT * NT];
    __shared__ float T[NT * 33];

    for (int q = tid; q < NT * 48; q += 192) {
        int i = q / 48, c = q - i * 48;
        ((float4*)K[i])[c] = ((const float4*)&Kt_ws[(b * NT + i) * Dd])[c];
        ((float4*)V[i])[c] = ((const float4*)&Vt_ws[(b * NT + i) * Dd])[c];
    }
    if (tid < NT) {
        int i = tid;
        float m = 0.f, pw = LRc;
        for (int nn = 0; nn < NT; nn++) {
            float v;
            if (nn < i) v = 0.f;
            else if (nn == i) { m = LRc; v = m; }
            else { pw *= ETAc; m = MDEC * m + pw; v = m; }
            mcc[nn * NT + i] = v;
        }
    }
    __syncthreads();
    for (int p = tid; p < NT * NT; p += 192) {       // Gram
        int i = p >> 5, j = p & 31;
        const float4* ki = (const float4*)K[i];
        const float4* kj = (const float4*)K[j];
        float s = 0.f;
        #pragma unroll 4
        for (int kk = 0; kk < 48; kk++) s += dot4(ki[kk], kj[kk]);
        G[p] = s;
    }
    __syncthreads();
    for (int p = tid; p < NT * NT; p += 192) {       // S in place over G
        int i = p >> 5, m = p & 31;
        G[p] = (m < i) ? mcc[(i - 1) * NT + m] * G[p] : 0.f;
    }
    __syncthreads();
    if (tid < NT) {                                   // T column solve
        int j = tid;
        T[j * 33 + j] = 1.f;
        for (int i = j + 1; i < NT; i++) {
            float s = 0.f;
            for (int m = j; m < i; m++) s += G[i * NT + m] * T[m * 33 + j];
            T[i * 33 + j] = -s;
        }
    }
    __syncthreads();
    {                                                 // err = T @ V (col-private)
        for (int i = 0; i < NT; i++) {
            float s = 0.f;
            for (int j = 0; j <= i; j++) s += T[i * 33 + j] * V[j][tid];
            Et_ws[(b * NT + i) * Dd + tid] = s;
        }
    }
}

// ---------------------------------------------------------------------------
// retrieve: grid B*32 (8 rows/block), 256 threads + fused head (last block).
// ---------------------------------------------------------------------------
__global__ __launch_bounds__(256) void retrieve(
    const float* __restrict__ x3_ws, const float* __restrict__ Ut_ws,
    const float* __restrict__ Et_ws, const float* __restrict__ ln2_g,
    const float* __restrict__ ln2_b, float* __restrict__ pooled,
    const float* __restrict__ Wc, const float* __restrict__ bc,
    float* __restrict__ out, unsigned int* __restrict__ ctr)
{
    int blk = blockIdx.x, b = blk >> 5, tile = blk & 31;
    int t0 = tile * RTT, n = tile;
    int tid = threadIdx.x;

    __shared__ float UT[NT][UPAD];       // odd pad: conflict-free lane-varying
    __shared__ __align__(16) float XS[RTT][PADD];
    __shared__ float WQ[RTT * NT];
    __shared__ float mv[RTT][2];
    __shared__ float PLD[Bb * Dd];
    __shared__ bool isLast;

    for (int q = tid; q < NT * Dd; q += 256) {
        int i = q / Dd, c = q - i * Dd;
        UT[i][c] = Ut_ws[(size_t)b * NT * Dd + q];
    }
    for (int q = tid; q < RTT * 48; q += 256) {
        int r = q / 48, c = q - r * 48;
        ((float4*)XS[r])[c] = ((const float4*)&x3_ws[((size_t)b * Tt + t0 + r) * Dd])[c];
    }
    __syncthreads();

    // dots: tid = r*32 + i ; w[r][i] = (x3_r . u~_i) * coef
    {
        int r = tid >> 5, i = tid & 31;
        const float* u = UT[i];
        const float* xr = XS[r];
        float s = 0.f;
        #pragma unroll 8
        for (int kk = 0; kk < Dd; kk++) s += u[kk] * xr[kk];
        float coef = (i <= n) ? memcoef(n, i) : 0.f;
        WQ[tid] = s * coef;
    }
    __syncthreads();

    // x4 = x3 + 0.5 * sum_i WQ * err_i
    if (tid < Dd) {
        float acc[RTT] = {};
        #pragma unroll 4
        for (int i = 0; i < NT; i++) {
            float e = Et_ws[(b * NT + i) * Dd + tid];
            #pragma unroll
            for (int r = 0; r < RTT; r++) acc[r] += WQ[r * NT + i] * e;
        }
        #pragma unroll
        for (int r = 0; r < RTT; r++) XS[r][tid] += 0.5f * acc[r];
    }
    __syncthreads();

    // LN2 stats
    {
        int r = tid >> 5, j = tid & 31;
        float s = 0.f, sq = 0.f;
        for (int d = j; d < Dd; d += 32) { float v = XS[r][d]; s += v; sq += v * v; }
        for (int off = 16; off > 0; off >>= 1) {
            s += __shfl_down(s, off, 32); sq += __shfl_down(sq, off, 32);
        }
        if (j == 0) {
            float mean = s / Dd;
            mv[r][0] = mean;
            mv[r][1] = rsqrtf(sq / Dd - mean * mean + EPSc);
        }
    }
    __syncthreads();

    if (tid < Dd) {
        float g = ln2_g[tid], bb = ln2_b[tid];
        float sum = 0.f;
        #pragma unroll
        for (int r = 0; r < RTT; r++)
            sum += (XS[r][tid] - mv[r][0]) * mv[r][1] * g + bb;
        atomicAdd(&pooled[b * Dd + tid], sum);
    }

    // -------- fused head: last block computes out = (pooled/T)@Wc + bc -----
    __threadfence();
    if (tid == 0) {
        unsigned int old = atomicAdd(ctr, 1u);
        isLast = (old == (unsigned)(Bb * 32 - 1));
    }
    __syncthreads();
    if (isLast) {
        __threadfence();
        for (int q = tid; q < Bb * Dd; q += 256)
            PLD[q] = *(volatile const float*)&pooled[q];
        __syncthreads();
        if (tid < Bb * NCc) {
            int bo = tid / NCc, c = tid - bo * NCc;
            float s = 0.f;
            for (int d = 0; d < Dd; d++) s += PLD[bo * Dd + d] * Wc[d * NCc + c];
            out[tid] = s * (1.0f / Tt) + bc[c];
        }
    }
}

extern "C" void kernel_launch(void* const* d_in, const int* in_sizes, int n_in,
                              void* d_out, int out_size, void* d_ws, size_t ws_size,
                              hipStream_t stream) {
    const float* x     = (const float*)d_in[0];
    const float* W_in  = (const float*)d_in[1];
    const float* b_in  = (const float*)d_in[2];
    const float* Wv_a  = (const float*)d_in[3];
    const float* bv_a  = (const float*)d_in[4];
    const float* Wo_a  = (const float*)d_in[5];
    const float* bo_a  = (const float*)d_in[6];
    const float* ln1_g = (const float*)d_in[7];
    const float* ln1_b = (const float*)d_in[8];
    const float* pw1_w = (const float*)d_in[9];
    const float* pw1_b = (const float*)d_in[10];
    const float* dw_w  = (const float*)d_in[11];
    const float* dw_b  = (const float*)d_in[12];
    const float* bn_s  = (const float*)d_in[13];
    const float* bn_b  = (const float*)d_in[14];
    const float* pw2_w = (const float*)d_in[15];
    const float* pw2_b = (const float*)d_in[16];
    const float* Wk_t  = (const float*)d_in[17];
    const float* Wv_t  = (const float*)d_in[18];
    const float* Wq_t  = (const float*)d_in[19];
    const float* Wk_d  = (const float*)d_in[20];
    const float* Wv_d  = (const float*)d_in[21];
    const float* Wq_d  = (const float*)d_in[22];
    const float* ln2_g = (const float*)d_in[23];
    const float* ln2_b = (const float*)d_in[24];
    const float* Wc    = (const float*)d_in[25];
    const float* bc    = (const float*)d_in[26];

    float* ws = (float*)d_ws;
    size_t off = 0;
    float* x3_ws   = ws + off; off += (size_t)Bb * Tt * Dd;
    float* Kd_ws   = ws + off; off += Bb * ND * Dd;
    float* Vd_ws   = ws + off; off += Bb * ND * Dd;   // -> err after delta_solve
    float* Ud_ws   = ws + off; off += Bb * ND * Dd;
    float* Kt_ws   = ws + off; off += Bb * NT * Dd;
    float* Vt_ws   = ws + off; off += Bb * NT * Dd;
    float* Et_ws   = ws + off; off += Bb * NT * Dd;   // theta err
    float* Ut_ws   = ws + off; off += Bb * NT * Dd;
    float* pooled  = ws + off; off += Bb * Dd;
    float* Wavo_ws = ws + off; off += Dd * Dd;
    float* WqtT    = ws + off; off += Dd * Dd;
    float* WqdT    = ws + off; off += Dd * Dd;
    float* b_avo   = ws + off; off += Dd;
    unsigned int* ctr = (unsigned int*)(ws + off); off += 1;

    setup<<<322, 192, 0, stream>>>(
        Wv_a, Wo_a, bv_a, bo_a, Wq_t, Wq_d,
        x, W_in, b_in, Wk_d, Wv_d,
        Wavo_ws, b_avo, WqtT, WqdT, Kd_ws, Vd_ws, pooled, ctr);
    delta_solve<<<Bb * 5, 192, 0, stream>>>(WqdT, Kd_ws, Vd_ws, Ud_ws);
    pipeline<<<Bb * 64, 192, 0, stream>>>(
        x, W_in, b_in, ln1_g, ln1_b, pw1_w, pw1_b, dw_w, dw_b,
        bn_s, bn_b, pw2_w, pw2_b, Wavo_ws, b_avo, Vd_ws, Ud_ws,
        Wk_t, Wv_t, WqtT, x3_ws, Kt_ws, Vt_ws, Ut_ws);
    theta_solve<<<Bb, 192, 0, stream>>>(Kt_ws, Vt_ws, Et_ws);
    retrieve<<<Bb * 32, 256, 0, stream>>>(
        x3_ws, Ut_ws, Et_ws, ln2_g, ln2_b, pooled, Wc, bc, (float*)d_out, ctr);
}